// Round 1
// baseline (1485.093 us; speedup 1.0000x reference)
//
#include <hip/hip_runtime.h>
#include <hip/hip_bf16.h>
#include <math.h>

#define H 768
#define B 256
#define T 100
#define G4 3072   // 4*H

typedef __attribute__((ext_vector_type(8))) short short8;
typedef __attribute__((ext_vector_type(4))) float f32x4;

static __device__ __forceinline__ float sigm(float x) {
    return 1.0f / (1.0f + __expf(-x));
}
static __device__ __forceinline__ float tanh_fast(float x) {
    // 1 - 2/(e^{2x}+1): saturates cleanly to +/-1, no inf/inf NaN
    return 1.0f - 2.0f / (__expf(2.0f * x) + 1.0f);
}

// ---------------- prep kernels (once per launch) ----------------

// grid: (3, 3072), block 256. k = bx*256+tid, r = by
__global__ void prep_weights(const float* __restrict__ Wih, const float* __restrict__ Whh,
                             const float* __restrict__ bih, const float* __restrict__ bhh,
                             __hip_bfloat16* __restrict__ Wc,    // 3072 x 768
                             __hip_bfloat16* __restrict__ Wcat,  // 3072 x 1536
                             float* __restrict__ bias)           // 3072
{
    int r = blockIdx.y;
    int k = blockIdx.x * 256 + threadIdx.x;
    float a = Wih[r * H + k];
    float b = Whh[r * H + k];
    Wc[r * H + k] = __float2bfloat16(a + b);
    Wcat[r * 1536 + k] = __float2bfloat16(a);
    Wcat[r * 1536 + H + k] = __float2bfloat16(b);
    if (blockIdx.x == 0 && threadIdx.x == 0) bias[r] = bih[r] + bhh[r];
}

// grid: (3, 80), block 256. Wp padded to 80 rows (zeros beyond 72)
__global__ void prep_post(const float* __restrict__ Wpost, __hip_bfloat16* __restrict__ Wp)
{
    int r = blockIdx.y;
    int k = blockIdx.x * 256 + threadIdx.x;
    Wp[r * H + k] = (r < 72) ? __float2bfloat16(Wpost[r * H + k]) : __float2bfloat16(0.0f);
}

// grid: (3, 256), block 256. A0 = [bf16(x0) | bf16(h0)], c_ws = c0
__global__ void prep_state(const float* __restrict__ src, const float* __restrict__ h0,
                           const float* __restrict__ c0,
                           __hip_bfloat16* __restrict__ A0,  // 256 x 1536
                           float* __restrict__ c_ws)         // 256 x 768
{
    int b = blockIdx.y;
    int k = blockIdx.x * 256 + threadIdx.x;
    A0[b * 1536 + k] = __float2bfloat16(src[(b * 16 + 15) * H + k]);   // src[:, -1, :]
    A0[b * 1536 + H + k] = __float2bfloat16(h0[b * H + k]);
    c_ws[b * H + k] = c0[b * H + k];
}

// ---------------- LSTM step: fused gates GEMM + cell ----------------
// grid: (48 j-tiles, 16 m-tiles), block 64 (1 wave).
// Wave computes 16 batches x 16 j, all 4 gates, then the cell update.
__global__ __launch_bounds__(64) void lstm_step(
    const __hip_bfloat16* __restrict__ A,   // B x K  (h_prev or [x0|h0])
    const __hip_bfloat16* __restrict__ W,   // 3072 x K (Wc or Wcat)
    const float* __restrict__ bias,         // 3072
    float* __restrict__ c,                  // B x H fp32 (in place)
    __hip_bfloat16* __restrict__ h_out,     // B x H bf16 (= outs[t])
    int K)
{
    const int jt = blockIdx.x;       // 0..47
    const int mt = blockIdx.y;       // 0..15
    const int lane = threadIdx.x;
    const int col = lane & 15;
    const int quad = lane >> 4;

    const short* Ap  = (const short*)A + (size_t)(mt * 16 + col) * K + quad * 8;
    const short* Wb  = (const short*)W;
    const short* Wp0 = Wb + (size_t)(0 * H + jt * 16 + col) * K + quad * 8;
    const short* Wp1 = Wb + (size_t)(1 * H + jt * 16 + col) * K + quad * 8;
    const short* Wp2 = Wb + (size_t)(2 * H + jt * 16 + col) * K + quad * 8;
    const short* Wp3 = Wb + (size_t)(3 * H + jt * 16 + col) * K + quad * 8;

    f32x4 acc0 = {0.f, 0.f, 0.f, 0.f};
    f32x4 acc1 = {0.f, 0.f, 0.f, 0.f};
    f32x4 acc2 = {0.f, 0.f, 0.f, 0.f};
    f32x4 acc3 = {0.f, 0.f, 0.f, 0.f};

    for (int k = 0; k < K; k += 32) {
        short8 a  = *(const short8*)(Ap + k);
        short8 b0 = *(const short8*)(Wp0 + k);
        short8 b1 = *(const short8*)(Wp1 + k);
        short8 b2 = *(const short8*)(Wp2 + k);
        short8 b3 = *(const short8*)(Wp3 + k);
        acc0 = __builtin_amdgcn_mfma_f32_16x16x32_bf16(a, b0, acc0, 0, 0, 0);
        acc1 = __builtin_amdgcn_mfma_f32_16x16x32_bf16(a, b1, acc1, 0, 0, 0);
        acc2 = __builtin_amdgcn_mfma_f32_16x16x32_bf16(a, b2, acc2, 0, 0, 0);
        acc3 = __builtin_amdgcn_mfma_f32_16x16x32_bf16(a, b3, acc3, 0, 0, 0);
    }

    const int j = jt * 16 + col;
    const float bi = bias[0 * H + j];
    const float bf = bias[1 * H + j];
    const float bg = bias[2 * H + j];
    const float bo = bias[3 * H + j];

#pragma unroll
    for (int r = 0; r < 4; ++r) {
        const int bidx = mt * 16 + quad * 4 + r;   // C/D: row = quad*4 + reg
        float ig = acc0[r] + bi;
        float fg = acc1[r] + bf;
        float gg = acc2[r] + bg;
        float og = acc3[r] + bo;
        float cold = c[bidx * H + j];
        float cn = sigm(fg) * cold + sigm(ig) * tanh_fast(gg);
        float hn = sigm(og) * tanh_fast(cn);
        c[bidx * H + j] = cn;
        h_out[bidx * H + j] = __float2bfloat16(hn);
    }
}

// ---------------- post projection: (T*B) x 72 <- (T*B) x 768 @ 768 x 72 ----------------
// grid: 1600 blocks of 64 (1 wave): M-tile 16 rows (m = t*256+b), N = 80 (5 tiles, o<72 written)
__global__ __launch_bounds__(64) void proj(
    const __hip_bfloat16* __restrict__ Hs,   // T x B x H
    const __hip_bfloat16* __restrict__ Wp,   // 80 x H (padded bf16)
    const float* __restrict__ bpost,         // 72
    float* __restrict__ out)                 // B x T x 72
{
    const int mt = blockIdx.x;
    const int lane = threadIdx.x;
    const int col = lane & 15;
    const int quad = lane >> 4;

    const short* Ap = (const short*)Hs + (size_t)(mt * 16 + col) * H + quad * 8;
    const short* Wb = (const short*)Wp;

    f32x4 acc[5];
#pragma unroll
    for (int nt = 0; nt < 5; ++nt) acc[nt] = (f32x4){0.f, 0.f, 0.f, 0.f};

    for (int k = 0; k < H; k += 32) {
        short8 a = *(const short8*)(Ap + k);
#pragma unroll
        for (int nt = 0; nt < 5; ++nt) {
            short8 b = *(const short8*)(Wb + (size_t)(nt * 16 + col) * H + quad * 8 + k);
            acc[nt] = __builtin_amdgcn_mfma_f32_16x16x32_bf16(a, b, acc[nt], 0, 0, 0);
        }
    }

#pragma unroll
    for (int nt = 0; nt < 5; ++nt) {
        const int o = nt * 16 + col;
        if (o < 72) {
            const float bb = bpost[o];
#pragma unroll
            for (int r = 0; r < 4; ++r) {
                const int m = mt * 16 + quad * 4 + r;
                const int t = m >> 8;        // m = t*256 + b
                const int b = m & 255;
                out[((size_t)b * T + t) * 72 + o] = acc[nt][r] + bb;
            }
        }
    }
}

// ---------------- launch ----------------

extern "C" void kernel_launch(void* const* d_in, const int* in_sizes, int n_in,
                              void* d_out, int out_size, void* d_ws, size_t ws_size,
                              hipStream_t stream) {
    const float* src   = (const float*)d_in[0];
    // d_in[1] = tgt: only its T dimension matters (hardcoded 100)
    const float* h0    = (const float*)d_in[2];
    const float* c0    = (const float*)d_in[3];
    const float* Wih   = (const float*)d_in[4];
    const float* Whh   = (const float*)d_in[5];
    const float* bih   = (const float*)d_in[6];
    const float* bhh   = (const float*)d_in[7];
    const float* Wpost = (const float*)d_in[8];
    const float* bpost = (const float*)d_in[9];
    float* out = (float*)d_out;

    char* ws = (char*)d_ws;
    __hip_bfloat16* Wcat = (__hip_bfloat16*)(ws + 0);          //  9,437,184 B
    __hip_bfloat16* Wc   = (__hip_bfloat16*)(ws + 9437184);    //  4,718,592 B
    float*          bias = (float*)(ws + 14155776);            //     12,288 B
    __hip_bfloat16* Wp   = (__hip_bfloat16*)(ws + 14168064);   //    122,880 B
    __hip_bfloat16* A0   = (__hip_bfloat16*)(ws + 14290944);   //    786,432 B
    float*          c_ws = (float*)(ws + 15077376);            //    786,432 B
    __hip_bfloat16* outs = (__hip_bfloat16*)(ws + 15863808);   // 39,321,600 B
    // total 55,185,408 B

    prep_weights<<<dim3(3, G4), 256, 0, stream>>>(Wih, Whh, bih, bhh, Wc, Wcat, bias);
    prep_post<<<dim3(3, 80), 256, 0, stream>>>(Wpost, Wp);
    prep_state<<<dim3(3, B), 256, 0, stream>>>(src, h0, c0, A0, c_ws);

    // step 0: gates = [x0|h0] @ [Wih|Whh]^T + bias   (K = 1536)
    lstm_step<<<dim3(48, 16), 64, 0, stream>>>(A0, Wcat, bias, c_ws, outs, 1536);
    // steps 1..99: gates = h @ (Wih+Whh)^T + bias     (K = 768)
    for (int t = 1; t < T; ++t) {
        lstm_step<<<dim3(48, 16), 64, 0, stream>>>(
            outs + (size_t)(t - 1) * B * H, Wc, bias, c_ws,
            outs + (size_t)t * B * H, H);
    }

    proj<<<1600, 64, 0, stream>>>(outs, Wp, bpost, out);
}